// Round 8
// baseline (216.207 us; speedup 1.0000x reference)
//
#include <hip/hip_runtime.h>
#include <hip/hip_bf16.h>

typedef __attribute__((ext_vector_type(8))) __bf16 bf16x8;
typedef __attribute__((ext_vector_type(4))) float f32x4;

// B=64, L=1024, H=512; M=65536, K=1024, N=512
// GEMM: 128x128 tile, BK=32, dbuf, 256 thr (4 waves 2Mx2N), ALL staging via
// global_load_lds (m97 lever). A stays fp32 in LDS (cvt at fragment read).
// Bank-conflict-free via source-side chunk swizzle (A: from enc addr perm,
// B: baked into Bimg). LDS = 2*16K (A fp32) + 2*8K (B bf16) = 48 KB -> 3 blk/CU.

#define NKT 32

// ---------------------------------------------------------------------------
// Pass 0a: q[b,h] = hidden[b,:] @ W_attn[0:512, h] + b_attn[h]   (fp32)
// ---------------------------------------------------------------------------
__global__ void qk(const float* __restrict__ hidden, const float* __restrict__ W_attn,
                   const float* __restrict__ b_attn, float* __restrict__ q) {
    int idx = blockIdx.x * 256 + threadIdx.x;   // < 32768
    int b = idx >> 9;
    int h = idx & 511;
    const float* hv = hidden + b * 512;
    float acc = b_attn[h];
#pragma unroll 8
    for (int k = 0; k < 512; ++k)
        acc = fmaf(hv[k], W_attn[(size_t)k * 512 + h], acc);
    q[idx] = acc;
}

// ---------------------------------------------------------------------------
// Pass 0b: Bimg[nt][kt][row][slot][e] = bf16(W2[k = kt*32 + c*8 + e][n = nt*128+row])
//   where c = slot ^ (row&3) ^ ((row>>2)&1)   (read-swizzle pre-baked)
// Flat: idx = (((nt*32+kt)*128+row)*4+slot)*8+e ; total 524288
// ---------------------------------------------------------------------------
__global__ void btk_img2(const float* __restrict__ W_attn, __bf16* __restrict__ Bimg) {
    int idx = blockIdx.x * 256 + threadIdx.x;
    int e    = idx & 7;
    int slot = (idx >> 3) & 3;
    int row  = (idx >> 5) & 127;
    int kt   = (idx >> 12) & 31;
    int nt   = idx >> 17;
    int c = slot ^ (row & 3) ^ ((row >> 2) & 1);
    int k = kt * 32 + c * 8 + e;
    int n = nt * 128 + row;
    Bimg[idx] = (__bf16)W_attn[(size_t)(512 + k) * 512 + n];
}

// ---------------------------------------------------------------------------
__device__ inline void gl_lds16(const void* g, void* l) {
    __builtin_amdgcn_global_load_lds(
        (const __attribute__((address_space(1))) void*)g,
        (__attribute__((address_space(3))) void*)l, 16, 0, 0);
}

// ---------------------------------------------------------------------------
// Pass 1: fused GEMM  S = enc @ W2, part = sum_n relu(S+q)*Wv (per 128-col blk)
// ---------------------------------------------------------------------------
__global__ __launch_bounds__(256, 3) void gemm_logits4(
    const float* __restrict__ A, const __bf16* __restrict__ Bimg,
    const float* __restrict__ q, const float* __restrict__ Wv,
    float* __restrict__ part)
{
    __shared__ float  As[2][4096];   // 2 x 16 KB: [row][slot(8)x4fp32], slot^=(row&7)
    __shared__ __bf16 Bs[2][4096];   // 2 x  8 KB: [row][slot(4)x8bf16], baked swz
    float* red = (float*)&As[0][0];  // overlay: As dead after K-loop

    const int bid = blockIdx.x;
    const int swz = (bid & 7) * 256 + (bid >> 3);   // XCD-chunked, bijective
    const int mt = swz >> 2;        // 0..511
    const int nt = swz & 3;         // 0..3

    const int t = threadIdx.x;
    const int lane = t & 63;
    const int wid = t >> 6;
    const int wm = wid >> 1;        // 0..1
    const int wn = wid & 1;         // 0..1

    // A staging: 4 gl_lds/thread; wave-instr j=wid*4+i covers rows j*8..j*8+7.
    // lane l -> row j*8+(l>>3), fetches global chunk (l&7)^(l>>3) -> LDS slot l&7
    const float* Asrc = A + (size_t)(mt * 128 + wid * 32 + (lane >> 3)) * 1024
                          + (((lane & 7) ^ (lane >> 3)) << 2);
    // B staging: 2 gl_lds/thread, linear from pre-baked Bimg
    const __bf16* Bsrc = Bimg + (size_t)nt * 32 * 4096 + (wid * 2) * 512 + lane * 8;

    f32x4 acc[4][4];
#pragma unroll
    for (int m = 0; m < 4; ++m)
#pragma unroll
        for (int n = 0; n < 4; ++n) acc[m][n] = (f32x4)0.0f;

#define STAGE(KT, BUF)                                                         \
    {                                                                          \
        _Pragma("unroll") for (int i = 0; i < 4; ++i)                          \
            gl_lds16(Asrc + (size_t)i * 8192 + (KT) * 32,                      \
                     &As[BUF][(wid * 4 + i) * 256]);                           \
        _Pragma("unroll") for (int i = 0; i < 2; ++i)                          \
            gl_lds16(Bsrc + (size_t)(KT) * 4096 + i * 512,                     \
                     &Bs[BUF][(wid * 2 + i) * 512]);                           \
    }

    STAGE(0, 0)
    __syncthreads();

    const int rsel = lane & 15;
    const int qq = lane >> 4;
    const int h = rsel & 7;
    const int s0 = (2 * qq) ^ h;          // LDS slot of K-chunk 2q
    const int s1 = (2 * qq + 1) ^ h;      // LDS slot of K-chunk 2q+1
    const int bslot = qq ^ (rsel & 3) ^ ((rsel >> 2) & 1);

    for (int kt = 0; kt < NKT; ++kt) {
        const int cur = kt & 1;
        if (kt + 1 < NKT) STAGE(kt + 1, cur ^ 1)   // direct-to-LDS, no reg trip

        bf16x8 af[4], bg[4];
#pragma unroll
        for (int m = 0; m < 4; ++m) {
            const int row = wm * 64 + m * 16 + rsel;
            float4 f0 = *(const float4*)&As[cur][row * 32 + s0 * 4];
            float4 f1 = *(const float4*)&As[cur][row * 32 + s1 * 4];
            bf16x8 v;
            v[0] = (__bf16)f0.x; v[1] = (__bf16)f0.y;
            v[2] = (__bf16)f0.z; v[3] = (__bf16)f0.w;
            v[4] = (__bf16)f1.x; v[5] = (__bf16)f1.y;
            v[6] = (__bf16)f1.z; v[7] = (__bf16)f1.w;
            af[m] = v;
        }
#pragma unroll
        for (int n = 0; n < 4; ++n) {
            const int row = wn * 64 + n * 16 + rsel;
            bg[n] = *(const bf16x8*)&Bs[cur][row * 32 + bslot * 8];
        }
#pragma unroll
        for (int m = 0; m < 4; ++m)
#pragma unroll
            for (int n = 0; n < 4; ++n)
                acc[m][n] = __builtin_amdgcn_mfma_f32_16x16x32_bf16(
                    af[m], bg[n], acc[m][n], 0, 0, 0);

        __syncthreads();   // drains STAGE (vmcnt) + frag reads (lgkm)
    }
#undef STAGE

    // Epilogue: part[row] = sum over this block's 128 cols of relu(acc+q)*Wv
    const float* qb = q + (mt >> 3) * 512;
    float qv[4], wvv[4];
#pragma unroll
    for (int n = 0; n < 4; ++n) {
        int gc = nt * 128 + wn * 64 + n * 16 + rsel;
        qv[n] = qb[gc];
        wvv[n] = Wv[gc];
    }

#pragma unroll
    for (int m = 0; m < 4; ++m) {
#pragma unroll
        for (int j = 0; j < 4; ++j) {
            float s = 0.f;
#pragma unroll
            for (int n = 0; n < 4; ++n) {
                float e = acc[m][n][j] + qv[n];
                s += (e > 0.f ? e : 0.f) * wvv[n];
            }
            s += __shfl_xor(s, 1);
            s += __shfl_xor(s, 2);
            s += __shfl_xor(s, 4);
            s += __shfl_xor(s, 8);
            if (rsel == 0) {
                int r = wm * 64 + m * 16 + (lane >> 4) * 4 + j;
                red[r * 2 + wn] = s;
            }
        }
    }
    __syncthreads();
    if (t < 128)
        part[(size_t)nt * 65536 + (size_t)mt * 128 + t] = red[t * 2] + red[t * 2 + 1];
}

// ---------------------------------------------------------------------------
// Pass 2: softmax over L=1024 per batch (sums the 4 col-block partials)
// ---------------------------------------------------------------------------
__global__ void softmax_k(const float* __restrict__ part, float* __restrict__ w) {
    __shared__ float smx[4];
    __shared__ float ssum[4];
    int b = blockIdx.x;
    int t = threadIdx.x;
    int lane = t & 63, wid = t >> 6;
    float v[4];
    float mx = -3.0e38f;
#pragma unroll
    for (int i = 0; i < 4; ++i) {
        int o = b * 1024 + t + i * 256;
        float s = part[o] + part[65536 + o] + part[131072 + o] + part[196608 + o];
        v[i] = s;
        mx = fmaxf(mx, s);
    }
#pragma unroll
    for (int off = 32; off >= 1; off >>= 1) mx = fmaxf(mx, __shfl_xor(mx, off));
    if (lane == 0) smx[wid] = mx;
    __syncthreads();
    mx = fmaxf(fmaxf(smx[0], smx[1]), fmaxf(smx[2], smx[3]));
    float e[4];
    float sum = 0.f;
#pragma unroll
    for (int i = 0; i < 4; ++i) { e[i] = __expf(v[i] - mx); sum += e[i]; }
#pragma unroll
    for (int off = 32; off >= 1; off >>= 1) sum += __shfl_xor(sum, off);
    if (lane == 0) ssum[wid] = sum;
    __syncthreads();
    float inv = 1.f / (ssum[0] + ssum[1] + ssum[2] + ssum[3]);
#pragma unroll
    for (int i = 0; i < 4; ++i) w[b * 1024 + t + i * 256] = e[i] * inv;
}

// ---------------------------------------------------------------------------
// Pass 3: partial context: ctxp[lc][b][e] = sum_{l in chunk lc} w[b,l]*enc[b,l,e]
// ---------------------------------------------------------------------------
__global__ void ctx_partial(const float* __restrict__ enc, const float* __restrict__ w,
                            float* __restrict__ ctxp) {
    int blk = blockIdx.x;   // 0..511
    int b = blk >> 3;
    int lc = blk & 7;
    int t = threadIdx.x;    // 256
    __shared__ float wl[128];
    if (t < 128) wl[t] = w[b * 1024 + lc * 128 + t];
    __syncthreads();
    float4 acc = {0.f, 0.f, 0.f, 0.f};
    const float* base = enc + ((size_t)(b * 1024 + lc * 128)) * 1024 + t * 4;
    for (int l = 0; l < 128; ++l) {
        float4 v = *(const float4*)(base + (size_t)l * 1024);
        float s = wl[l];
        acc.x += s * v.x; acc.y += s * v.y; acc.z += s * v.z; acc.w += s * v.w;
    }
    *(float4*)(ctxp + (size_t)(lc * 64 + b) * 1024 + t * 4) = acc;
}

// ---------------------------------------------------------------------------
// Pass 4: out[b][e] = sum_lc ctxp[lc][b][e]
// ---------------------------------------------------------------------------
__global__ void ctx_sum(const float* __restrict__ ctxp, float* __restrict__ out) {
    int idx = blockIdx.x * 256 + threadIdx.x;   // < 16384 (float4 each)
    float4 a = {0.f, 0.f, 0.f, 0.f};
#pragma unroll
    for (int lc = 0; lc < 8; ++lc) {
        float4 v = *(const float4*)(ctxp + (size_t)lc * 65536 + (size_t)idx * 4);
        a.x += v.x; a.y += v.y; a.z += v.z; a.w += v.w;
    }
    *(float4*)(out + (size_t)idx * 4) = a;
}

// ---------------------------------------------------------------------------
extern "C" void kernel_launch(void* const* d_in, const int* in_sizes, int n_in,
                              void* d_out, int out_size, void* d_ws, size_t ws_size,
                              hipStream_t stream) {
    const float* hidden = (const float*)d_in[0];
    const float* enc    = (const float*)d_in[1];
    const float* W_attn = (const float*)d_in[2];
    const float* b_attn = (const float*)d_in[3];
    const float* W_v    = (const float*)d_in[4];
    float* out = (float*)d_out;

    char* ws = (char*)d_ws;
    float*  q    = (float*)(ws + 0);          // 128 KB  [64][512]
    __bf16* Bimg = (__bf16*)(ws + 131072);    // 1 MB    [4][32][128][4][8]
    float*  part = (float*)(ws + 1179648);    // 1 MB    [4][65536]
    float*  wts  = (float*)(ws + 2228224);    // 256 KB  [64][1024]
    float*  ctxp = (float*)(ws + 2490368);    // 2 MB    [8][64][1024]

    qk<<<128, 256, 0, stream>>>(hidden, W_attn, b_attn, q);
    btk_img2<<<2048, 256, 0, stream>>>(W_attn, Bimg);
    gemm_logits4<<<2048, 256, 0, stream>>>(enc, Bimg, q, W_v, part);
    softmax_k<<<64, 256, 0, stream>>>(part, wts);
    ctx_partial<<<512, 256, 0, stream>>>(enc, wts, ctxp);
    ctx_sum<<<64, 256, 0, stream>>>(ctxp, out);
}

// Round 10
// 206.473 us; speedup vs baseline: 1.0471x; 1.0471x over previous
//
#include <hip/hip_runtime.h>
#include <hip/hip_bf16.h>

typedef __attribute__((ext_vector_type(8))) __bf16 bf16x8;
typedef __attribute__((ext_vector_type(4))) float f32x4;

// B=64, L=1024, H=512; M=65536, K=1024, N=512
// GEMM: 128x128 tile, BK=32, 256 thr (4 waves 2Mx2N), reg-staged with
// DEPTH-2 load pipeline (two reg sets, counted vmcnt) + raw lgkm-only
// barriers (loads stay in flight across barriers = T4).
// LDS: combined rows [128][64 bf16] = 128 B: slots 0-3 = A k-chunks,
// 4-7 = B k-chunks, phys_slot = logical ^ (row&7)  (R4-proven 0-conflict).

// ---------------------------------------------------------------------------
// Pass 0a: q[b,h] = hidden[b,:] @ W_attn[0:512, h] + b_attn[h]   (fp32)
// ---------------------------------------------------------------------------
__global__ void qk(const float* __restrict__ hidden, const float* __restrict__ W_attn,
                   const float* __restrict__ b_attn, float* __restrict__ q) {
    int idx = blockIdx.x * 256 + threadIdx.x;   // < 32768
    int b = idx >> 9;
    int h = idx & 511;
    const float* hv = hidden + b * 512;
    float acc = b_attn[h];
#pragma unroll 8
    for (int k = 0; k < 512; ++k)
        acc = fmaf(hv[k], W_attn[(size_t)k * 512 + h], acc);
    q[idx] = acc;
}

// ---------------------------------------------------------------------------
// Pass 0b: Bt[n][k] = bf16(W_attn[512 + k][n])   -> [512][1024] bf16 (B^T)
// ---------------------------------------------------------------------------
__global__ void btk(const float* __restrict__ W_attn, __bf16* __restrict__ Bt) {
    int idx = blockIdx.x * 256 + threadIdx.x;   // < 524288
    int n = idx >> 10;
    int k = idx & 1023;
    Bt[idx] = (__bf16)W_attn[(size_t)(512 + k) * 512 + n];
}

// ---------------------------------------------------------------------------
// Pass 1: fused GEMM  S = enc @ W2, part = sum_n relu(S+q)*Wv (per 128-col blk)
// ---------------------------------------------------------------------------
__global__ __launch_bounds__(256, 3) void gemm_logits5(
    const float* __restrict__ A, const __bf16* __restrict__ Bt,
    const float* __restrict__ q, const float* __restrict__ Wv,
    float* __restrict__ part)
{
    __shared__ __bf16 Ls[2][128][64];   // 2 x 16 KB combined A|B tile
    __shared__ float red[128][2];       // 1 KB epilogue

    const int bid = blockIdx.x;
    const int swz = (bid & 7) * 256 + (bid >> 3);   // XCD-chunked, bijective
    const int mt = swz >> 2;        // 0..511
    const int nt = swz & 3;         // 0..3

    const int t = threadIdx.x;
    const int lane = t & 63;
    const int wid = t >> 6;
    const int wm = wid >> 1;        // 0..1
    const int wn = wid & 1;         // 0..1

    // staging: thread -> row = t>>1 (0..127), half = t&1 (16 elems of K)
    const int srow = t >> 1;
    const int shalf = t & 1;
    const float* Ag = A + (size_t)(mt * 128 + srow) * 1024 + shalf * 16;
    const __bf16* Bg = Bt + (size_t)(nt * 128 + srow) * 1024 + shalf * 16;
    const int rx = srow & 7;
    // phys slots for this thread's writes (logical A: 2h,2h+1; B: 4+2h,4+2h+1)
    const int wa0 = (shalf * 2) ^ rx,     wa1 = (shalf * 2 + 1) ^ rx;
    const int wb0 = (4 + shalf * 2) ^ rx, wb1 = (4 + shalf * 2 + 1) ^ rx;

    f32x4 acc[4][4];
#pragma unroll
    for (int m = 0; m < 4; ++m)
#pragma unroll
        for (int n = 0; n < 4; ++n) acc[m][n] = (f32x4)0.0f;

    float4 aS[2][4];    // two load-reg sets (indices always literal)
    bf16x8 bS[2][2];

#define LOADS(P, KT)                                                           \
    {                                                                          \
        const float* ap = Ag + (size_t)(KT) * 32;                              \
        aS[P][0] = *(const float4*)(ap);                                       \
        aS[P][1] = *(const float4*)(ap + 4);                                   \
        aS[P][2] = *(const float4*)(ap + 8);                                   \
        aS[P][3] = *(const float4*)(ap + 12);                                  \
        const __bf16* bp = Bg + (size_t)(KT) * 32;                             \
        bS[P][0] = *(const bf16x8*)(bp);                                       \
        bS[P][1] = *(const bf16x8*)(bp + 8);                                   \
    }

#define WRITES(P, BUF)                                                         \
    {                                                                          \
        bf16x8 v0, v1;                                                         \
        v0[0] = (__bf16)aS[P][0].x; v0[1] = (__bf16)aS[P][0].y;                \
        v0[2] = (__bf16)aS[P][0].z; v0[3] = (__bf16)aS[P][0].w;                \
        v0[4] = (__bf16)aS[P][1].x; v0[5] = (__bf16)aS[P][1].y;                \
        v0[6] = (__bf16)aS[P][1].z; v0[7] = (__bf16)aS[P][1].w;                \
        v1[0] = (__bf16)aS[P][2].x; v1[1] = (__bf16)aS[P][2].y;                \
        v1[2] = (__bf16)aS[P][2].z; v1[3] = (__bf16)aS[P][2].w;                \
        v1[4] = (__bf16)aS[P][3].x; v1[5] = (__bf16)aS[P][3].y;                \
        v1[6] = (__bf16)aS[P][3].z; v1[7] = (__bf16)aS[P][3].w;                \
        *(bf16x8*)&Ls[BUF][srow][wa0 * 8] = v0;                                \
        *(bf16x8*)&Ls[BUF][srow][wa1 * 8] = v1;                                \
        *(bf16x8*)&Ls[BUF][srow][wb0 * 8] = bS[P][0];                          \
        *(bf16x8*)&Ls[BUF][srow][wb1 * 8] = bS[P][1];                          \
    }

#define BARRIER()                                                              \
    do {                                                                       \
        asm volatile("s_waitcnt lgkmcnt(0)" ::: "memory");                     \
        __builtin_amdgcn_s_barrier();                                          \
        __builtin_amdgcn_sched_barrier(0);                                     \
    } while (0)

    const int rsel = lane & 15;
    const int qq = lane >> 4;              // k-chunk 0..3

#define FRAGS_MFMA(CUR)                                                        \
    {                                                                          \
        bf16x8 af[4];                                                          \
        _Pragma("unroll") for (int m = 0; m < 4; ++m) {                        \
            const int row = wm * 64 + m * 16 + rsel;                           \
            af[m] = *(const bf16x8*)&Ls[CUR][row][(qq ^ (row & 7)) * 8];       \
        }                                                                      \
        __builtin_amdgcn_s_setprio(1);                                         \
        _Pragma("unroll") for (int n = 0; n < 4; ++n) {                        \
            const int row = wn * 64 + n * 16 + rsel;                           \
            bf16x8 bg = *(const bf16x8*)&Ls[CUR][row][((4 + qq) ^ (row & 7)) * 8]; \
            _Pragma("unroll") for (int m = 0; m < 4; ++m)                      \
                acc[m][n] = __builtin_amdgcn_mfma_f32_16x16x32_bf16(           \
                    af[m], bg, acc[m][n], 0, 0, 0);                            \
        }                                                                      \
        __builtin_amdgcn_s_setprio(0);                                         \
    }

    // ---- prologue: tiles 0,1 -> sets S0,S1; S0 -> LDS buf0 ----
    LOADS(0, 0)
    LOADS(1, 1)
    WRITES(0, 0)                 // compiler: counted vmcnt (S1 in flight)
    BARRIER();

    // ---- main: 32 K-steps, unrolled x2 for compile-time set indices ----
    for (int ki = 0; ki < 15; ++ki) {
        const int kt = ki * 2;
        // even step: read L0; reload S0 <- kt+2; write S1 (tile kt+1) -> L1
        LOADS(0, kt + 2)
        FRAGS_MFMA(0)
        WRITES(1, 1)
        BARRIER();
        // odd step: read L1; reload S1 <- kt+3; write S0 (tile kt+2) -> L0
        LOADS(1, kt + 3)
        FRAGS_MFMA(1)
        WRITES(0, 0)
        BARRIER();
    }
    // kt = 30: read L0; write S1 (tile 31) -> L1
    FRAGS_MFMA(0)
    WRITES(1, 1)
    BARRIER();
    // kt = 31: read L1
    FRAGS_MFMA(1)

#undef LOADS
#undef WRITES
#undef FRAGS_MFMA

    // ---- epilogue: part[row] = sum over this block's 128 cols of relu(acc+q)*Wv
    const float* qb = q + (mt >> 3) * 512;
    float qv[4], wvv[4];
#pragma unroll
    for (int n = 0; n < 4; ++n) {
        int gc = nt * 128 + wn * 64 + n * 16 + rsel;
        qv[n] = qb[gc];
        wvv[n] = Wv[gc];
    }

#pragma unroll
    for (int m = 0; m < 4; ++m) {
#pragma unroll
        for (int j = 0; j < 4; ++j) {
            float s = 0.f;
#pragma unroll
            for (int n = 0; n < 4; ++n) {
                float e = acc[m][n][j] + qv[n];
                s += (e > 0.f ? e : 0.f) * wvv[n];
            }
            s += __shfl_xor(s, 1);
            s += __shfl_xor(s, 2);
            s += __shfl_xor(s, 4);
            s += __shfl_xor(s, 8);
            if (rsel == 0) {
                int r = wm * 64 + m * 16 + (lane >> 4) * 4 + j;
                red[r][wn] = s;
            }
        }
    }
    __syncthreads();
    if (t < 128)
        part[(size_t)nt * 65536 + (size_t)mt * 128 + t] = red[t][0] + red[t][1];
}

// ---------------------------------------------------------------------------
// Pass 2: softmax over L=1024 per batch (sums the 4 col-block partials)
// ---------------------------------------------------------------------------
__global__ void softmax_k(const float* __restrict__ part, float* __restrict__ w) {
    __shared__ float smx[4];
    __shared__ float ssum[4];
    int b = blockIdx.x;
    int t = threadIdx.x;
    int lane = t & 63, wid = t >> 6;
    float v[4];
    float mx = -3.0e38f;
#pragma unroll
    for (int i = 0; i < 4; ++i) {
        int o = b * 1024 + t + i * 256;
        float s = part[o] + part[65536 + o] + part[131072 + o] + part[196608 + o];
        v[i] = s;
        mx = fmaxf(mx, s);
    }
#pragma unroll
    for (int off = 32; off >= 1; off >>= 1) mx = fmaxf(mx, __shfl_xor(mx, off));
    if (lane == 0) smx[wid] = mx;
    __syncthreads();
    mx = fmaxf(fmaxf(smx[0], smx[1]), fmaxf(smx[2], smx[3]));
    float e[4];
    float sum = 0.f;
#pragma unroll
    for (int i = 0; i < 4; ++i) { e[i] = __expf(v[i] - mx); sum += e[i]; }
#pragma unroll
    for (int off = 32; off >= 1; off >>= 1) sum += __shfl_xor(sum, off);
    if (lane == 0) ssum[wid] = sum;
    __syncthreads();
    float inv = 1.f / (ssum[0] + ssum[1] + ssum[2] + ssum[3]);
#pragma unroll
    for (int i = 0; i < 4; ++i) w[b * 1024 + t + i * 256] = e[i] * inv;
}

// ---------------------------------------------------------------------------
// Pass 3: partial context: ctxp[lc][b][e] = sum_{l in chunk lc} w[b,l]*enc[b,l,e]
// ---------------------------------------------------------------------------
__global__ void ctx_partial(const float* __restrict__ enc, const float* __restrict__ w,
                            float* __restrict__ ctxp) {
    int blk = blockIdx.x;   // 0..511
    int b = blk >> 3;
    int lc = blk & 7;
    int t = threadIdx.x;    // 256
    __shared__ float wl[128];
    if (t < 128) wl[t] = w[b * 1024 + lc * 128 + t];
    __syncthreads();
    float4 acc = {0.f, 0.f, 0.f, 0.f};
    const float* base = enc + ((size_t)(b * 1024 + lc * 128)) * 1024 + t * 4;
    for (int l = 0; l < 128; ++l) {
        float4 v = *(const float4*)(base + (size_t)l * 1024);
        float s = wl[l];
        acc.x += s * v.x; acc.y += s * v.y; acc.z += s * v.z; acc.w += s * v.w;
    }
    *(float4*)(ctxp + (size_t)(lc * 64 + b) * 1024 + t * 4) = acc;
}

// ---------------------------------------------------------------------------
// Pass 4: out[b][e] = sum_lc ctxp[lc][b][e]
// ---------------------------------------------------------------------------
__global__ void ctx_sum(const float* __restrict__ ctxp, float* __restrict__ out) {
    int idx = blockIdx.x * 256 + threadIdx.x;   // < 16384 (float4 each)
    float4 a = {0.f, 0.f, 0.f, 0.f};
#pragma unroll
    for (int lc = 0; lc < 8; ++lc) {
        float4 v = *(const float4*)(ctxp + (size_t)lc * 65536 + (size_t)idx * 4);
        a.x += v.x; a.y += v.y; a.z += v.z; a.w += v.w;
    }
    *(float4*)(out + (size_t)idx * 4) = a;
}

// ---------------------------------------------------------------------------
extern "C" void kernel_launch(void* const* d_in, const int* in_sizes, int n_in,
                              void* d_out, int out_size, void* d_ws, size_t ws_size,
                              hipStream_t stream) {
    const float* hidden = (const float*)d_in[0];
    const float* enc    = (const float*)d_in[1];
    const float* W_attn = (const float*)d_in[2];
    const float* b_attn = (const float*)d_in[3];
    const float* W_v    = (const float*)d_in[4];
    float* out = (float*)d_out;

    char* ws = (char*)d_ws;
    float*  q    = (float*)(ws + 0);          // 128 KB  [64][512]
    __bf16* Bt   = (__bf16*)(ws + 131072);    // 1 MB    [512][1024]
    float*  part = (float*)(ws + 1179648);    // 1 MB    [4][65536]
    float*  wts  = (float*)(ws + 2228224);    // 256 KB  [64][1024]
    float*  ctxp = (float*)(ws + 2490368);    // 2 MB    [8][64][1024]

    qk<<<128, 256, 0, stream>>>(hidden, W_attn, b_attn, q);
    btk<<<2048, 256, 0, stream>>>(W_attn, Bt);
    gemm_logits5<<<2048, 256, 0, stream>>>(enc, Bt, q, W_v, part);
    softmax_k<<<64, 256, 0, stream>>>(part, wts);
    ctx_partial<<<512, 256, 0, stream>>>(enc, wts, ctxp);
    ctx_sum<<<64, 256, 0, stream>>>(ctxp, out);
}

// Round 11
// 185.650 us; speedup vs baseline: 1.1646x; 1.1122x over previous
//
#include <hip/hip_runtime.h>
#include <hip/hip_bf16.h>

typedef __attribute__((ext_vector_type(8))) __bf16 bf16x8;
typedef __attribute__((ext_vector_type(4))) float f32x4;

// B=64, L=1024, H=512; M=65536, K=1024, N=512
// GEMM: 256x256 tile (2x the FLOP/byte of 128x128 -> halves L2/L3 traffic,
// the measured ~10 TB/s delivery invariant), BK=32 dbuf, 512 thr = 8 waves
// (2M x 4N, 128x64 per wave). 512 blocks = exactly 2/CU co-resident.
// LDS: 2 M-rows per 128-B row, phys_slot = logical ^ (lrow&7) (R4 0-conflict map).

#define NKT 32

// ---------------------------------------------------------------------------
// Pass 0a: q[b,h] = hidden[b,:] @ W_attn[0:512, h] + b_attn[h]   (fp32)
// ---------------------------------------------------------------------------
__global__ void qk(const float* __restrict__ hidden, const float* __restrict__ W_attn,
                   const float* __restrict__ b_attn, float* __restrict__ q) {
    int idx = blockIdx.x * 256 + threadIdx.x;   // < 32768
    int b = idx >> 9;
    int h = idx & 511;
    const float* hv = hidden + b * 512;
    float acc = b_attn[h];
#pragma unroll 8
    for (int k = 0; k < 512; ++k)
        acc = fmaf(hv[k], W_attn[(size_t)k * 512 + h], acc);
    q[idx] = acc;
}

// ---------------------------------------------------------------------------
// Pass 0b: Bt[n][k] = bf16(W_attn[512 + k][n])   -> [512][1024] bf16 (B^T)
// ---------------------------------------------------------------------------
__global__ void btk(const float* __restrict__ W_attn, __bf16* __restrict__ Bt) {
    int idx = blockIdx.x * 256 + threadIdx.x;   // < 524288
    int n = idx >> 10;
    int k = idx & 1023;
    Bt[idx] = (__bf16)W_attn[(size_t)(512 + k) * 512 + n];
}

// ---------------------------------------------------------------------------
// Pass 1: fused GEMM  S = enc @ W2, part = sum_n relu(S+q)*Wv (per 256-col blk)
// ---------------------------------------------------------------------------
__global__ __launch_bounds__(512, 2) void gemm_logits6(
    const float* __restrict__ A, const __bf16* __restrict__ Bt,
    const float* __restrict__ q, const float* __restrict__ Wv,
    float* __restrict__ part)
{
    __shared__ __bf16 Als[2][128][64];   // 32 KB (256 rows x 32 k, 2 rows/LDS-row)
    __shared__ __bf16 Bls[2][128][64];   // 32 KB
    float* red = (float*)&Als[0][0][0];  // 4 KB overlay, Als dead after K-loop

    const int bid = blockIdx.x;
    const int swz = (bid & 7) * 64 + (bid >> 3);   // 512 blocks, bijective
    const int mt = swz >> 1;        // 0..255
    const int nt = swz & 1;         // 0..1

    const int t = threadIdx.x;
    const int lane = t & 63;
    const int wid = t >> 6;          // 0..7
    const int wm = wid >> 2;         // 0..1  (128 M-rows each)
    const int wn = wid & 3;          // 0..3  (64 N-cols each)

    // staging: thread -> row = t>>1 (0..255), k-half kh = t&1 (16 elems)
    const int srow = t >> 1;
    const int kh = t & 1;
    const float*  Ag = A  + (size_t)(mt * 256 + srow) * 1024 + kh * 16;
    const __bf16* Bg = Bt + (size_t)(nt * 256 + srow) * 1024 + kh * 16;
    const int slrow = srow >> 1;              // LDS row 0..127
    const int sl7 = slrow & 7;
    const int ws0 = ((srow & 1) * 4 + kh * 2) ^ sl7;       // phys slot, chunk 0
    const int ws1 = ((srow & 1) * 4 + kh * 2 + 1) ^ sl7;   // phys slot, chunk 1

    f32x4 acc[8][4];
#pragma unroll
    for (int m = 0; m < 8; ++m)
#pragma unroll
        for (int n = 0; n < 4; ++n) acc[m][n] = (f32x4)0.0f;

    float4 av[4];
    bf16x8 bv[2];

#define LOADS(KT)                                                              \
    {                                                                          \
        const float* ap = Ag + (size_t)(KT) * 32;                              \
        av[0] = *(const float4*)(ap);                                          \
        av[1] = *(const float4*)(ap + 4);                                      \
        av[2] = *(const float4*)(ap + 8);                                      \
        av[3] = *(const float4*)(ap + 12);                                     \
        const __bf16* bp = Bg + (size_t)(KT) * 32;                             \
        bv[0] = *(const bf16x8*)(bp);                                          \
        bv[1] = *(const bf16x8*)(bp + 8);                                      \
    }

#define WRITES(BUF)                                                            \
    {                                                                          \
        bf16x8 v0, v1;                                                         \
        v0[0] = (__bf16)av[0].x; v0[1] = (__bf16)av[0].y;                      \
        v0[2] = (__bf16)av[0].z; v0[3] = (__bf16)av[0].w;                      \
        v0[4] = (__bf16)av[1].x; v0[5] = (__bf16)av[1].y;                      \
        v0[6] = (__bf16)av[1].z; v0[7] = (__bf16)av[1].w;                      \
        v1[0] = (__bf16)av[2].x; v1[1] = (__bf16)av[2].y;                      \
        v1[2] = (__bf16)av[2].z; v1[3] = (__bf16)av[2].w;                      \
        v1[4] = (__bf16)av[3].x; v1[5] = (__bf16)av[3].y;                      \
        v1[6] = (__bf16)av[3].z; v1[7] = (__bf16)av[3].w;                      \
        *(bf16x8*)&Als[BUF][slrow][ws0 * 8] = v0;                              \
        *(bf16x8*)&Als[BUF][slrow][ws1 * 8] = v1;                              \
        *(bf16x8*)&Bls[BUF][slrow][ws0 * 8] = bv[0];                           \
        *(bf16x8*)&Bls[BUF][slrow][ws1 * 8] = bv[1];                           \
    }

    const int rsel = lane & 15;
    const int qq = lane >> 4;                          // k-chunk 0..3
    const int pa = (((rsel & 1) * 4 + qq) ^ (rsel >> 1)) * 8;  // frag phys byte/2
    const int rhalf = rsel >> 1;                       // lrow offset within frag

    // ---- prologue ----
    LOADS(0)
    WRITES(0)
    __syncthreads();

    for (int kt = 0; kt < NKT; ++kt) {
        const int cur = kt & 1;
        if (kt + 1 < NKT) LOADS(kt + 1)   // issue early: hides under MFMA

        bf16x8 af[8], bg[4];
#pragma unroll
        for (int m = 0; m < 8; ++m)
            af[m] = *(const bf16x8*)&Als[cur][wm * 64 + m * 8 + rhalf][pa];
#pragma unroll
        for (int n = 0; n < 4; ++n)
            bg[n] = *(const bf16x8*)&Bls[cur][wn * 32 + n * 8 + rhalf][pa];

        __builtin_amdgcn_s_setprio(1);
#pragma unroll
        for (int m = 0; m < 8; ++m)
#pragma unroll
            for (int n = 0; n < 4; ++n)
                acc[m][n] = __builtin_amdgcn_mfma_f32_16x16x32_bf16(
                    af[m], bg[n], acc[m][n], 0, 0, 0);
        __builtin_amdgcn_s_setprio(0);

        if (kt + 1 < NKT) {
            WRITES(cur ^ 1)
            __syncthreads();
        }
    }
#undef LOADS
#undef WRITES

    __syncthreads();   // Als reads done before red overlay

    // ---- epilogue: per-row sum over this block's 256 cols of relu(acc+q)*Wv
    const float* qb = q + (mt >> 2) * 512;   // batch = mt*256/1024
    float qv[4], wvv[4];
#pragma unroll
    for (int n = 0; n < 4; ++n) {
        int gc = nt * 256 + wn * 64 + n * 16 + rsel;
        qv[n] = qb[gc];
        wvv[n] = Wv[gc];
    }

#pragma unroll
    for (int m = 0; m < 8; ++m) {
#pragma unroll
        for (int j = 0; j < 4; ++j) {
            float s = 0.f;
#pragma unroll
            for (int n = 0; n < 4; ++n) {
                float e = acc[m][n][j] + qv[n];
                s += (e > 0.f ? e : 0.f) * wvv[n];
            }
            s += __shfl_xor(s, 1);
            s += __shfl_xor(s, 2);
            s += __shfl_xor(s, 4);
            s += __shfl_xor(s, 8);
            if (rsel == 0) {
                int r = wm * 128 + m * 16 + (lane >> 4) * 4 + j;
                red[r * 4 + wn] = s;
            }
        }
    }
    __syncthreads();
    if (t < 256)
        part[(size_t)nt * 65536 + (size_t)mt * 256 + t] =
            red[t * 4] + red[t * 4 + 1] + red[t * 4 + 2] + red[t * 4 + 3];
}

// ---------------------------------------------------------------------------
// Pass 2: softmax over L=1024 per batch (sums the 2 col-block partials)
// ---------------------------------------------------------------------------
__global__ void softmax_k(const float* __restrict__ part, float* __restrict__ w) {
    __shared__ float smx[4];
    __shared__ float ssum[4];
    int b = blockIdx.x;
    int t = threadIdx.x;
    int lane = t & 63, wid = t >> 6;
    float v[4];
    float mx = -3.0e38f;
#pragma unroll
    for (int i = 0; i < 4; ++i) {
        int o = b * 1024 + t + i * 256;
        float s = part[o] + part[65536 + o];
        v[i] = s;
        mx = fmaxf(mx, s);
    }
#pragma unroll
    for (int off = 32; off >= 1; off >>= 1) mx = fmaxf(mx, __shfl_xor(mx, off));
    if (lane == 0) smx[wid] = mx;
    __syncthreads();
    mx = fmaxf(fmaxf(smx[0], smx[1]), fmaxf(smx[2], smx[3]));
    float e[4];
    float sum = 0.f;
#pragma unroll
    for (int i = 0; i < 4; ++i) { e[i] = __expf(v[i] - mx); sum += e[i]; }
#pragma unroll
    for (int off = 32; off >= 1; off >>= 1) sum += __shfl_xor(sum, off);
    if (lane == 0) ssum[wid] = sum;
    __syncthreads();
    float inv = 1.f / (ssum[0] + ssum[1] + ssum[2] + ssum[3]);
#pragma unroll
    for (int i = 0; i < 4; ++i) w[b * 1024 + t + i * 256] = e[i] * inv;
}

// ---------------------------------------------------------------------------
// Pass 3: partial context: ctxp[lc][b][e] = sum_{l in chunk lc} w[b,l]*enc[b,l,e]
// ---------------------------------------------------------------------------
__global__ void ctx_partial(const float* __restrict__ enc, const float* __restrict__ w,
                            float* __restrict__ ctxp) {
    int blk = blockIdx.x;   // 0..511
    int b = blk >> 3;
    int lc = blk & 7;
    int t = threadIdx.x;    // 256
    __shared__ float wl[128];
    if (t < 128) wl[t] = w[b * 1024 + lc * 128 + t];
    __syncthreads();
    float4 acc = {0.f, 0.f, 0.f, 0.f};
    const float* base = enc + ((size_t)(b * 1024 + lc * 128)) * 1024 + t * 4;
    for (int l = 0; l < 128; ++l) {
        float4 v = *(const float4*)(base + (size_t)l * 1024);
        float s = wl[l];
        acc.x += s * v.x; acc.y += s * v.y; acc.z += s * v.z; acc.w += s * v.w;
    }
    *(float4*)(ctxp + (size_t)(lc * 64 + b) * 1024 + t * 4) = acc;
}

// ---------------------------------------------------------------------------
// Pass 4: out[b][e] = sum_lc ctxp[lc][b][e]
// ---------------------------------------------------------------------------
__global__ void ctx_sum(const float* __restrict__ ctxp, float* __restrict__ out) {
    int idx = blockIdx.x * 256 + threadIdx.x;   // < 16384 (float4 each)
    float4 a = {0.f, 0.f, 0.f, 0.f};
#pragma unroll
    for (int lc = 0; lc < 8; ++lc) {
        float4 v = *(const float4*)(ctxp + (size_t)lc * 65536 + (size_t)idx * 4);
        a.x += v.x; a.y += v.y; a.z += v.z; a.w += v.w;
    }
    *(float4*)(out + (size_t)idx * 4) = a;
}

// ---------------------------------------------------------------------------
extern "C" void kernel_launch(void* const* d_in, const int* in_sizes, int n_in,
                              void* d_out, int out_size, void* d_ws, size_t ws_size,
                              hipStream_t stream) {
    const float* hidden = (const float*)d_in[0];
    const float* enc    = (const float*)d_in[1];
    const float* W_attn = (const float*)d_in[2];
    const float* b_attn = (const float*)d_in[3];
    const float* W_v    = (const float*)d_in[4];
    float* out = (float*)d_out;

    char* ws = (char*)d_ws;
    float*  q    = (float*)(ws + 0);          // 128 KB  [64][512]
    __bf16* Bt   = (__bf16*)(ws + 131072);    // 1 MB    [512][1024]
    float*  part = (float*)(ws + 1179648);    // 512 KB  [2][65536]
    float*  wts  = (float*)(ws + 1703936);    // 256 KB  [64][1024]
    float*  ctxp = (float*)(ws + 1966080);    // 2 MB    [8][64][1024]

    qk<<<128, 256, 0, stream>>>(hidden, W_attn, b_attn, q);
    btk<<<2048, 256, 0, stream>>>(W_attn, Bt);
    gemm_logits6<<<512, 512, 0, stream>>>(enc, Bt, q, W_v, part);
    softmax_k<<<64, 256, 0, stream>>>(part, wts);
    ctx_partial<<<512, 256, 0, stream>>>(enc, wts, ctxp);
    ctx_sum<<<64, 256, 0, stream>>>(ctxp, out);
}